// Round 11
// baseline (309.670 us; speedup 1.0000x reference)
//
#include <hip/hip_runtime.h>
#include <hip/hip_bf16.h>

// B=8,G=16,N=1024,C=256.
// R16: R15 + halved A-duplication + vectorized v reads.
//  R15's LDS model (matches 52us): per CU-tile ~3072cy A-frag b128 (8 col-strip
//  waves x 16 reads, 8x duplicated), ~2230cy scalar vsm reads, ~1480 u16,
//  ~1280 cvt. Fixes:
//   1) 4-wave blocks (256 thr), 64 cols/wave: (256,2) -> 2 blk/CU -> 8 waves
//      -> 256-VGPR cap (R12-R14: arg2 = blocks/CU). Bf[4][8]=128 VGPR + acc 32
//      fits. A-frag traffic halves (4 strips).
//   2) planar vsmP[3][256]: phase-B v = 6 ds_read_b128/wave-tile vs 24 scalars.
//  Rest identical to R15 (passing, absmax 9.8e-4): gload_lds fp32 land ->
//  cvt-once -> swizzled bf16 bx[2]; 2 barriers/tile; B-frags once per block.
// wfc_cvt / vn_linear / ws layout unchanged (passing since R7).

#define NQ 1024
#define CQ 256
#define RT 32            // rows per tile
#define TILES 8          // tiles per block (8*32 = 256 rows/block)
#define WB_OFF 131072    // ws float offset of bf16 Wfc (after 512 KB partials)

typedef __attribute__((ext_vector_type(8))) short bf16x8;
typedef __attribute__((ext_vector_type(4))) float f32x4;

__device__ __forceinline__ ushort2 pk2(float a, float b) {
    __hip_bfloat162 h = __float22bfloat162_rn(make_float2(a, b));  // v_cvt_pk_bf16_f32
    ushort2 r;
    __builtin_memcpy(&r, &h, sizeof(r));
    return r;
}
__device__ __forceinline__ float bf2f(ushort h) {
    union { unsigned u; float f; } v; v.u = ((unsigned)h) << 16;
    return v.f;
}

// async 16B HBM->LDS; per-lane global src, wave-uniform LDS base (+lane*16 by HW)
__device__ __forceinline__ void gload16(const float* g, float* l) {
    __builtin_amdgcn_global_load_lds(
        (const __attribute__((address_space(1))) unsigned int*)g,
        (__attribute__((address_space(3))) unsigned int*)l, 16, 0, 0);
}

// lgkm-only barrier: LDS writes visible, global loads stay in flight.
__device__ __forceinline__ void bar_lgkm() {
    __builtin_amdgcn_sched_barrier(0);
    asm volatile("s_waitcnt lgkmcnt(0)" ::: "memory");
    __builtin_amdgcn_sched_barrier(0);
    __builtin_amdgcn_s_barrier();
    __builtin_amdgcn_sched_barrier(0);
}

// ---- kernel 1: Wfc fp32 -> bf16 fragment-major WbT[k>>3][col][k&7] ----
__global__ __launch_bounds__(256)
void wfc_cvt(const float* __restrict__ Wfc, ushort* __restrict__ WbT) {
    const int i = blockIdx.x * 256 + threadIdx.x;   // 16384 threads x 4 floats
    const int o = i >> 6;            // output col (Wfc row) 0..255
    const int k4 = (i & 63) * 4;     // k start 0..252
    float4 v = *reinterpret_cast<const float4*>(Wfc + (size_t)o * CQ + k4);
    ushort2 a0 = pk2(v.x, v.y), a1 = pk2(v.z, v.w);
    ushort4 pk = { a0.x, a0.y, a1.x, a1.y };
    *reinterpret_cast<ushort4*>(WbT + ((size_t)(k4 >> 3) * CQ + o) * 8 + (k4 & 7)) = pk;
}

// ---- kernel 2: fused q=x@Wfc^T, e=exp(q), partial Z/S accumulation ----
__global__ __launch_bounds__(256, 2)
void attn_pool_partial(const float* __restrict__ x, const float* __restrict__ vs,
                       const ushort* __restrict__ WbT, float* __restrict__ ws) {
    __shared__ __align__(16) float land[RT * CQ];        // 32 KB fp32 landing
    __shared__ __align__(16) char  bx[2][RT * 512];      // 2 x 16 KB bf16 tiles (swizzled)
    __shared__ __align__(16) float vsmP[3][TILES * RT];  // 3 KB planar v

    const int t = threadIdx.x;                     // 0..255
    const int id = blockIdx.x;                     // 0..511
    const int bg = id >> 2;
    const int ntg = id & 3;
    const int nb = ntg * (TILES * RT);             // block's 256-row slab

    const int w = t >> 6, lane = t & 63;           // 4 waves
    const int quad = lane >> 4, l16 = lane & 15;

    const float* xb = x + (size_t)bg * NQ * CQ;
    const float* vb = vs + (size_t)bg * NQ * 3;

    // ---- prologue group 1: B-fragments, 64 cols/wave (L2-hot, live all block) ----
    bf16x8 Bf[4][8];                               // [ci][ks] = 128 VGPR
    const int bcol0 = w * 64 + l16;
    #pragma unroll
    for (int ci = 0; ci < 4; ++ci) {
        #pragma unroll
        for (int ks = 0; ks < 8; ++ks) {
            const size_t fo = (size_t)(ks * 4 + quad) * (CQ * 8);
            Bf[ci][ks] = *reinterpret_cast<const bf16x8*>(
                WbT + fo + (size_t)(bcol0 + ci * 16) * 8);
        }
    }
    __builtin_amdgcn_sched_barrier(0);

    // ---- prologue group 2: v slab (256 rows x 3 = 768 floats = 192 float4) ----
    const bool vload = (t < 192);
    float4 vreg;
    if (vload) vreg = reinterpret_cast<const float4*>(vb + (size_t)nb * 3)[t];
    __builtin_amdgcn_sched_barrier(0);

    // ---- prologue group 3: stage tile 0 fp32 (async, no regs; 8 rows/wave) ----
    #pragma unroll
    for (int p = 0; p < 8; ++p) {
        const int row = p * 4 + w;                 // wave-uniform row
        gload16(xb + (size_t)(nb + row) * CQ + lane * 4, &land[row * CQ]);
    }
    __builtin_amdgcn_sched_barrier(0);
    asm volatile("s_waitcnt vmcnt(0)" ::: "memory");
    __builtin_amdgcn_sched_barrier(0);
    // scatter v interleaved->planar (once per block)
    if (vload) {
        float va[4] = { vreg.x, vreg.y, vreg.z, vreg.w };
        #pragma unroll
        for (int j = 0; j < 4; ++j) {
            const int e = t * 4 + j;               // global elem = row*3 + d
            vsmP[e % 3][e / 3] = va[j];
        }
    }
    bar_lgkm();    // land + vsmP visible

    // ---- cvt tile 0 -> bx[0] ----
    {
        char* dst = bx[0];
        #pragma unroll
        for (int p = 0; p < 8; ++p) {
            const int row = p * 4 + w;
            float4 v4 = *reinterpret_cast<const float4*>(&land[row * CQ + lane * 4]);
            ushort2 a0 = pk2(v4.x, v4.y), a1 = pk2(v4.z, v4.w);
            ushort4 pk = { a0.x, a0.y, a1.x, a1.y };
            *reinterpret_cast<ushort4*>(dst + row * 512 + ((lane * 8) ^ ((row & 7) << 4))) = pk;
        }
    }
    bar_lgkm();

    // running partials across all 8 tiles (per ci strip)
    float rZ[4] = {0.f, 0.f, 0.f, 0.f};
    float rS0[4] = {0.f, 0.f, 0.f, 0.f};
    float rS1[4] = {0.f, 0.f, 0.f, 0.f};
    float rS2[4] = {0.f, 0.f, 0.f, 0.f};

    for (int i = 0; i < TILES; ++i) {
        const char* bxp = bx[i & 1];

        // ---- issue next tile's fp32 staging (flies under this tile's compute) ----
        if (i < TILES - 1) {
            const int tb = nb + (i + 1) * RT;
            #pragma unroll
            for (int p = 0; p < 8; ++p) {
                const int row = p * 4 + w;
                gload16(xb + (size_t)(tb + row) * CQ + lane * 4, &land[row * CQ]);
            }
        }
        __builtin_amdgcn_sched_barrier(0);

        // ---- MFMA over K=256: A-frag = one b128; 4 col-sets per wave ----
        f32x4 acc[2][4];
        #pragma unroll
        for (int mi = 0; mi < 2; ++mi)
            #pragma unroll
            for (int ci = 0; ci < 4; ++ci) acc[mi][ci] = (f32x4){0.f, 0.f, 0.f, 0.f};

        __builtin_amdgcn_s_setprio(1);
        #pragma unroll
        for (int ks = 0; ks < 8; ++ks) {
            const int kkb = ks * 64 + quad * 16;   // colbyte of this frag
            #pragma unroll
            for (int mi = 0; mi < 2; ++mi) {
                const int row = mi * 16 + l16;
                bf16x8 a = *reinterpret_cast<const bf16x8*>(
                    bxp + row * 512 + (kkb ^ ((row & 7) << 4)));
                #pragma unroll
                for (int ci = 0; ci < 4; ++ci)
                    acc[mi][ci] = __builtin_amdgcn_mfma_f32_16x16x32_bf16(a, Bf[ci][ks], acc[mi][ci], 0, 0, 0);
            }
        }
        __builtin_amdgcn_s_setprio(0);

        // ---- phase B: e = exp(q); accumulate partials ----
        #pragma unroll
        for (int mi = 0; mi < 2; ++mi) {
            const int rbase = mi * 16 + quad * 4;
            const int vrow = i * RT + rbase;
            f32x4 v0 = *reinterpret_cast<const f32x4*>(&vsmP[0][vrow]);
            f32x4 v1 = *reinterpret_cast<const f32x4*>(&vsmP[1][vrow]);
            f32x4 v2 = *reinterpret_cast<const f32x4*>(&vsmP[2][vrow]);
            #pragma unroll
            for (int ci = 0; ci < 4; ++ci) {
                const int xc = w * 64 + ci * 16 + l16;
                #pragma unroll
                for (int r = 0; r < 4; ++r) {
                    const int row = rbase + r;
                    float e = __expf(acc[mi][ci][r]);
                    ushort h = *reinterpret_cast<const ushort*>(
                        bxp + row * 512 + ((xc * 2) ^ ((row & 7) << 4)));
                    float xv = bf2f(h);
                    rZ[ci] += e;
                    float p = e * xv;
                    rS0[ci] = fmaf(p, v0[r], rS0[ci]);
                    rS1[ci] = fmaf(p, v1[r], rS1[ci]);
                    rS2[ci] = fmaf(p, v2[r], rS2[ci]);
                }
            }
        }

        // ---- tile boundary: drain staging, sync, cvt next tile, sync ----
        __builtin_amdgcn_sched_barrier(0);
        asm volatile("s_waitcnt vmcnt(0)" ::: "memory");
        __builtin_amdgcn_sched_barrier(0);
        __builtin_amdgcn_s_barrier();
        __builtin_amdgcn_sched_barrier(0);

        if (i < TILES - 1) {
            char* dst = bx[(i + 1) & 1];
            #pragma unroll
            for (int p = 0; p < 8; ++p) {
                const int row = p * 4 + w;
                float4 v4 = *reinterpret_cast<const float4*>(&land[row * CQ + lane * 4]);
                ushort2 a0 = pk2(v4.x, v4.y), a1 = pk2(v4.z, v4.w);
                ushort4 pk = { a0.x, a0.y, a1.x, a1.y };
                *reinterpret_cast<ushort4*>(dst + row * 512 + ((lane * 8) ^ ((row & 7) << 4))) = pk;
            }
            bar_lgkm();
        }
    }

    // ---- reduce over quads and ONE atomicAdd per col per block ----
    #pragma unroll
    for (int ci = 0; ci < 4; ++ci) {
        float z = rZ[ci], s0 = rS0[ci], s1 = rS1[ci], s2 = rS2[ci];
        #pragma unroll
        for (int off = 16; off < 64; off <<= 1) {
            z  += __shfl_xor(z,  off);
            s0 += __shfl_xor(s0, off);
            s1 += __shfl_xor(s1, off);
            s2 += __shfl_xor(s2, off);
        }
        if (quad == 0) {
            const int col = w * 64 + ci * 16 + l16;
            float* p = ws + ((size_t)bg * CQ + col) * 4;
            atomicAdd(&p[0], z);
            atomicAdd(&p[1], s0);
            atomicAdd(&p[2], s1);
            atomicAdd(&p[3], s2);
        }
    }
}

// ---- kernel 3: out[bg][o][d] = sum_c Wvn[o][c] * S[bg][c][d] / Z[bg][c] ----
__global__ __launch_bounds__(256, 4)
void vn_linear(const float* __restrict__ ws, const float* __restrict__ Wvn,
               float* __restrict__ out) {
    __shared__ float Tsm[CQ][3];
    const int bg = blockIdx.x, t = threadIdx.x;
    {
        f32x4 z4 = *reinterpret_cast<const f32x4*>(ws + ((size_t)bg * CQ + t) * 4);
        float inv = 1.f / z4[0];
        Tsm[t][0] = z4[1] * inv;
        Tsm[t][1] = z4[2] * inv;
        Tsm[t][2] = z4[3] * inv;
    }
    __syncthreads();
    const float* wr = Wvn + (size_t)t * CQ;
    float a0 = 0.f, a1 = 0.f, a2 = 0.f;
    #pragma unroll
    for (int c = 0; c < CQ; c += 4) {
        float4 w4 = *reinterpret_cast<const float4*>(wr + c);
        a0 += w4.x * Tsm[c + 0][0] + w4.y * Tsm[c + 1][0]
            + w4.z * Tsm[c + 2][0] + w4.w * Tsm[c + 3][0];
        a1 += w4.x * Tsm[c + 0][1] + w4.y * Tsm[c + 1][1]
            + w4.z * Tsm[c + 2][1] + w4.w * Tsm[c + 3][1];
        a2 += w4.x * Tsm[c + 0][2] + w4.y * Tsm[c + 1][2]
            + w4.z * Tsm[c + 2][2] + w4.w * Tsm[c + 3][2];
    }
    float* op = out + ((size_t)bg * CQ + t) * 3;
    op[0] = a0; op[1] = a1; op[2] = a2;
}

extern "C" void kernel_launch(void* const* d_in, const int* in_sizes, int n_in,
                              void* d_out, int out_size, void* d_ws, size_t ws_size,
                              hipStream_t stream) {
    const float* x   = (const float*)d_in[0];  // [8,16,1024,256]
    const float* vs  = (const float*)d_in[1];  // [8,16,1,1024,3]
    const float* Wfc = (const float*)d_in[2];  // [256,256]
    // d_in[3] = b_fc: constant along softmax axis n -> no effect, unused
    const float* Wvn = (const float*)d_in[4];  // [256,256]
    float* out = (float*)d_out;                // [8,16,256,3]
    float* ws  = (float*)d_ws;                 // 512 KB partials + 128 KB bf16 Wfc

    ushort* WbT = (ushort*)(ws + WB_OFF);

    (void)hipMemsetAsync(ws, 0, (size_t)128 * CQ * 4 * sizeof(float), stream);
    wfc_cvt<<<dim3(64), dim3(256), 0, stream>>>(Wfc, WbT);
    attn_pool_partial<<<dim3(512), dim3(256), 0, stream>>>(x, vs, WbT, ws);
    vn_linear<<<dim3(128), dim3(256), 0, stream>>>(ws, Wvn, out);
}